// Round 1
// baseline (288.023 us; speedup 1.0000x reference)
//
#include <hip/hip_runtime.h>
#include <cstdint>
#include <cstddef>

#define NTOK 8192      // B*S
#define SLEN 2048
#define DM   768
#define NH   12
#define DKH  64

typedef __attribute__((ext_vector_type(8))) short bf16x8;
typedef __attribute__((ext_vector_type(4))) float f32x4;

__device__ __forceinline__ float b2f(unsigned short u) {
  return __uint_as_float(((unsigned)u) << 16);
}
__device__ __forceinline__ unsigned short f2b(float f) {
  unsigned u = __float_as_uint(f);
  u += 0x7fffu + ((u >> 16) & 1u);   // RNE (no NaN inputs here)
  return (unsigned short)(u >> 16);
}

__device__ __forceinline__ void gld16(const void* g, void* l) {
  __builtin_amdgcn_global_load_lds(
      (const __attribute__((address_space(1))) void*)g,
      (__attribute__((address_space(3))) void*)l, 16, 0, 0);
}

// ---------------- fp32 -> bf16 cast ----------------
__global__ void cast_bf16_kernel(const float* __restrict__ in,
                                 unsigned short* __restrict__ out, int n8) {
  int i = blockIdx.x * blockDim.x + threadIdx.x;
  if (i >= n8) return;
  const float4* p = (const float4*)(in + (size_t)i * 8);
  float4 a = p[0], b = p[1];
  union { unsigned short h[8]; bf16x8 v; } u;
  u.h[0] = f2b(a.x); u.h[1] = f2b(a.y); u.h[2] = f2b(a.z); u.h[3] = f2b(a.w);
  u.h[4] = f2b(b.x); u.h[5] = f2b(b.y); u.h[6] = f2b(b.z); u.h[7] = f2b(b.w);
  *(bf16x8*)(out + (size_t)i * 8) = u.v;
}

// ---------------- RoPE (in-place on bf16 Q or K) ----------------
// thread handles 8 consecutive bf16 = 4 (even,odd) pairs within one head
__global__ void rope_kernel(unsigned short* __restrict__ X,
                            const int* __restrict__ pos, int total) {
  int idx = blockIdx.x * blockDim.x + threadIdx.x;
  if (idx >= total) return;
  int row = idx / 96, ch = idx - row * 96;   // 96 = DM/8 chunks per token
  int s = row & (SLEN - 1);
  int col = ch * 8;
  int p0 = (col & 63) >> 1;                  // pair index base within head
  float ps = (float)pos[s];
  unsigned short* ptr = X + (size_t)row * DM + col;
  bf16x8 v = *(bf16x8*)ptr;
  float f[8];
#pragma unroll
  for (int i = 0; i < 8; ++i) f[i] = b2f(((unsigned short*)&v)[i]);
  union { unsigned short h[8]; bf16x8 v; } o;
#pragma unroll
  for (int i = 0; i < 4; ++i) {
    float p = (float)(p0 + i);
    float freq = exp2f(p * -0.4152410118609203f);  // 10000^(-p/32)
    float ang = ps * freq;
    float sn, cs;
    __sincosf(ang, &sn, &cs);
    float x1 = f[2 * i], x2 = f[2 * i + 1];
    o.h[2 * i]     = f2b(x1 * cs - x2 * sn);
    o.h[2 * i + 1] = f2b(x1 * sn + x2 * cs);
  }
  *(bf16x8*)ptr = o.v;
}

// ---------------- GEMM: C[M][N] = sum_k A[m][k] * B[n][k] ----------------
// 128x128 tile, BK=64, 4 waves (2x2), each wave 64x64 via 4x4 16x16x32 frags.
// LDS XOR-swizzle: elem(r,k) stored at r*64 + (k ^ ((r&7)<<3)); staging uses
// pre-swizzled GLOBAL source so global_load_lds's linear dest matches.
__device__ __forceinline__ void stv(float* p, float v) { *p = v; }
__device__ __forceinline__ void stv(unsigned short* p, float v) { *p = f2b(v); }

template <typename CT>
__global__ __launch_bounds__(256, 2) void gemm_bt_kernel(
    const unsigned short* __restrict__ A,
    const unsigned short* __restrict__ B0, const unsigned short* __restrict__ B1,
    const unsigned short* __restrict__ B2,
    CT* __restrict__ C0, CT* __restrict__ C1, CT* __restrict__ C2,
    int N, int K) {
  const unsigned short* Bp = (blockIdx.z == 0) ? B0 : (blockIdx.z == 1) ? B1 : B2;
  CT* Cp = (blockIdx.z == 0) ? C0 : (blockIdx.z == 1) ? C1 : C2;
  const int tid = threadIdx.x, wid = tid >> 6, lane = tid & 63;
  const int lrow = lane & 15, lk8 = (lane >> 4) << 3;
  const int m0 = blockIdx.y * 128, n0 = blockIdx.x * 128;
  const int wm = (wid >> 1) * 64, wn = (wid & 1) * 64;
  const int sr = lane >> 3, sc = (lane & 7) * 8;
  __shared__ unsigned short At[128 * 64];
  __shared__ unsigned short Bt[128 * 64];
  f32x4 acc[4][4] = {};
  for (int k0 = 0; k0 < K; k0 += 64) {
    __syncthreads();
#pragma unroll
    for (int i = 0; i < 4; ++i) {
      int r = (wid * 4 + i) * 8 + sr;
      int k = sc ^ ((r & 7) << 3);
      gld16(A  + (size_t)(m0 + r) * K + k0 + k, &At[(wid * 4 + i) * 512]);
      gld16(Bp + (size_t)(n0 + r) * K + k0 + k, &Bt[(wid * 4 + i) * 512]);
    }
    __syncthreads();
    bf16x8 af[2][4], bfr[2][4];
#pragma unroll
    for (int ks = 0; ks < 2; ++ks)
#pragma unroll
      for (int mi = 0; mi < 4; ++mi) {
        int ra = wm + mi * 16 + lrow;
        af[ks][mi]  = *(const bf16x8*)&At[ra * 64 + ((ks * 32 + lk8) ^ ((ra & 7) << 3))];
        int rb = wn + mi * 16 + lrow;
        bfr[ks][mi] = *(const bf16x8*)&Bt[rb * 64 + ((ks * 32 + lk8) ^ ((rb & 7) << 3))];
      }
#pragma unroll
    for (int ks = 0; ks < 2; ++ks)
#pragma unroll
      for (int mi = 0; mi < 4; ++mi)
#pragma unroll
        for (int ni = 0; ni < 4; ++ni)
          acc[mi][ni] = __builtin_amdgcn_mfma_f32_16x16x32_bf16(
              af[ks][mi], bfr[ks][ni], acc[mi][ni], 0, 0, 0);
  }
  // C/D layout: col = lane&15, row = (lane>>4)*4 + reg   [m89-verified]
#pragma unroll
  for (int mi = 0; mi < 4; ++mi)
#pragma unroll
    for (int ni = 0; ni < 4; ++ni)
#pragma unroll
      for (int r = 0; r < 4; ++r) {
        int row = m0 + wm + mi * 16 + (lane >> 4) * 4 + r;
        int col = n0 + wn + ni * 16 + lrow;
        stv(Cp + (size_t)row * N + col, acc[mi][ni][r]);
      }
}

// ---------------- causal flash attention ----------------
// grid (SLEN/64, B*NH); 4 waves, wave w owns q rows [w*16, w*16+16) of the tile.
__global__ __launch_bounds__(256, 2) void attn_kernel(
    const unsigned short* __restrict__ Q, const unsigned short* __restrict__ Kg,
    const unsigned short* __restrict__ V, unsigned short* __restrict__ O) {
  const int qt = blockIdx.x, bh = blockIdx.y;
  const int b = bh / NH, h = bh - b * NH;
  const size_t base = ((size_t)b * SLEN) * DM + h * DKH;
  const int tid = threadIdx.x, wid = tid >> 6, lane = tid & 63;
  const int lrow = lane & 15, g = lane >> 4, lk8 = g * 8;
  __shared__ unsigned short Kt[64 * 64];          // swizzled [kr][d]
  __shared__ unsigned short Vt[64 * 64];          // swizzled transposed [d][kr]
  __shared__ unsigned short Pl[4][16 * 64];       // per-wave P, swizzled [qr][kv]

  // Q fragments in registers, pre-scaled by 1/sqrt(dk)=0.125 (exact in bf16)
  const int qrow = qt * 64 + wid * 16 + lrow;
  bf16x8 qf[2];
#pragma unroll
  for (int ks = 0; ks < 2; ++ks) {
    union { unsigned short h[8]; bf16x8 v; } u;
    u.v = *(const bf16x8*)&Q[base + (size_t)qrow * DM + ks * 32 + lk8];
#pragma unroll
    for (int j = 0; j < 8; ++j) u.h[j] = f2b(b2f(u.h[j]) * 0.125f);
    qf[ks] = u.v;
  }

  f32x4 oacc[4] = {};
  float m_run[4], l_run[4];
#pragma unroll
  for (int r = 0; r < 4; ++r) { m_run[r] = -1e30f; l_run[r] = 0.f; }

  for (int kt = 0; kt <= qt; ++kt) {
    __syncthreads();
    // stage K via global_load_lds, source pre-swizzled
#pragma unroll
    for (int i = 0; i < 2; ++i) {
      int kr = (wid * 2 + i) * 8 + (lane >> 3);
      int d = ((lane & 7) * 8) ^ ((kr & 7) << 3);
      gld16(Kg + base + (size_t)(kt * 64 + kr) * DM + d, &Kt[(wid * 2 + i) * 512]);
    }
    // stage V transposed: uniform-row ds_writes, XOR swizzle -> conflict-free
#pragma unroll
    for (int j8 = 0; j8 < 2; ++j8) {
      int c0 = wid * 16 + j8 * 8;
      bf16x8 vv = *(const bf16x8*)&V[base + (size_t)(kt * 64 + lane) * DM + c0];
#pragma unroll
      for (int jj = 0; jj < 8; ++jj) {
        Vt[(c0 + jj) * 64 + (lane ^ (jj << 3))] = ((unsigned short*)&vv)[jj];
      }
    }
    __syncthreads();

    // S = Q K^T (A-frag rows = q, B-frag rows = k rows of K)
    f32x4 sa[4] = {};
#pragma unroll
    for (int ks = 0; ks < 2; ++ks)
#pragma unroll
      for (int ni = 0; ni < 4; ++ni) {
        int krow = ni * 16 + lrow;
        bf16x8 kf = *(const bf16x8*)&Kt[krow * 64 + ((ks * 32 + lk8) ^ ((krow & 7) << 3))];
        sa[ni] = __builtin_amdgcn_mfma_f32_16x16x32_bf16(qf[ks], kf, sa[ni], 0, 0, 0);
      }

    // wave-parallel online softmax over rows (16-lane fragment groups)
    float p[4][4], mx[4];
#pragma unroll
    for (int r = 0; r < 4; ++r) mx[r] = -1e30f;
    const bool diag = (kt == qt);
#pragma unroll
    for (int ni = 0; ni < 4; ++ni)
#pragma unroll
      for (int r = 0; r < 4; ++r) {
        float s = sa[ni][r];
        if (diag && (ni * 16 + lrow > wid * 16 + g * 4 + r)) s = -1e30f;
        p[ni][r] = s;
        mx[r] = fmaxf(mx[r], s);
      }
#pragma unroll
    for (int r = 0; r < 4; ++r)
#pragma unroll
      for (int off = 1; off < 16; off <<= 1)
        mx[r] = fmaxf(mx[r], __shfl_xor(mx[r], off));
    float rs[4];
#pragma unroll
    for (int r = 0; r < 4; ++r) {
      float mn = fmaxf(m_run[r], mx[r]);
      float scl = __expf(m_run[r] - mn);
      m_run[r] = mn;
      l_run[r] *= scl;
#pragma unroll
      for (int ni = 0; ni < 4; ++ni) oacc[ni][r] *= scl;
      float sum = 0.f;
#pragma unroll
      for (int ni = 0; ni < 4; ++ni) { p[ni][r] = __expf(p[ni][r] - mn); sum += p[ni][r]; }
      rs[r] = sum;
    }
#pragma unroll
    for (int r = 0; r < 4; ++r) {
#pragma unroll
      for (int off = 1; off < 16; off <<= 1) rs[r] += __shfl_xor(rs[r], off);
      l_run[r] += rs[r];
    }

    // P (C-layout) -> wave-private LDS (A-layout source), bf16
#pragma unroll
    for (int ni = 0; ni < 4; ++ni)
#pragma unroll
      for (int r = 0; r < 4; ++r) {
        int qr = g * 4 + r;
        int kv = ni * 16 + lrow;
        Pl[wid][qr * 64 + (kv ^ ((qr & 7) << 3))] = f2b(p[ni][r]);
      }

    // O += P V  (B-frag from transposed V: col = d, k-slots = kv rows)
#pragma unroll
    for (int ks = 0; ks < 2; ++ks) {
      bf16x8 pf = *(const bf16x8*)&Pl[wid][lrow * 64 + ((ks * 32 + lk8) ^ ((lrow & 7) << 3))];
#pragma unroll
      for (int ni = 0; ni < 4; ++ni) {
        int d = ni * 16 + lrow;
        bf16x8 vf = *(const bf16x8*)&Vt[d * 64 + ((ks * 32 + lk8) ^ ((d & 7) << 3))];
        oacc[ni] = __builtin_amdgcn_mfma_f32_16x16x32_bf16(pf, vf, oacc[ni], 0, 0, 0);
      }
    }
  }

#pragma unroll
  for (int ni = 0; ni < 4; ++ni)
#pragma unroll
    for (int r = 0; r < 4; ++r) {
      int srow = qt * 64 + wid * 16 + g * 4 + r;
      O[base + (size_t)srow * DM + ni * 16 + lrow] = f2b(oacc[ni][r] / l_run[r]);
    }
}

// ---------------- launch ----------------
extern "C" void kernel_launch(void* const* d_in, const int* in_sizes, int n_in,
                              void* d_out, int out_size, void* d_ws, size_t ws_size,
                              hipStream_t stream) {
  const float* x  = (const float*)d_in[0];
  const float* Wq = (const float*)d_in[1];
  const float* Wk = (const float*)d_in[2];
  const float* Wv = (const float*)d_in[3];
  const float* Wo = (const float*)d_in[4];
  const int* pos  = (const int*)d_in[5];
  float* out = (float*)d_out;

  char* ws = (char*)d_ws;
  size_t off = 0;
  auto carve = [&](size_t bytes) -> void* {
    void* p = ws + off;
    off += (bytes + 255) & ~(size_t)255;
    return p;
  };
  unsigned short* xb  = (unsigned short*)carve((size_t)NTOK * DM * 2);
  unsigned short* wqb = (unsigned short*)carve((size_t)DM * DM * 2);
  unsigned short* wkb = (unsigned short*)carve((size_t)DM * DM * 2);
  unsigned short* wvb = (unsigned short*)carve((size_t)DM * DM * 2);
  unsigned short* wob = (unsigned short*)carve((size_t)DM * DM * 2);
  unsigned short* Qb  = (unsigned short*)carve((size_t)NTOK * DM * 2);
  unsigned short* Kb  = (unsigned short*)carve((size_t)NTOK * DM * 2);
  unsigned short* Vb  = (unsigned short*)carve((size_t)NTOK * DM * 2);
  unsigned short* Ab  = (unsigned short*)carve((size_t)NTOK * DM * 2);

  const int n8x = NTOK * DM / 8;   // 786432
  const int n8w = DM * DM / 8;     // 73728
  cast_bf16_kernel<<<dim3((n8x + 255) / 256), dim3(256), 0, stream>>>(x, xb, n8x);
  cast_bf16_kernel<<<dim3((n8w + 255) / 256), dim3(256), 0, stream>>>(Wq, wqb, n8w);
  cast_bf16_kernel<<<dim3((n8w + 255) / 256), dim3(256), 0, stream>>>(Wk, wkb, n8w);
  cast_bf16_kernel<<<dim3((n8w + 255) / 256), dim3(256), 0, stream>>>(Wv, wvb, n8w);
  cast_bf16_kernel<<<dim3((n8w + 255) / 256), dim3(256), 0, stream>>>(Wo, wob, n8w);

  // fused QKV projection: grid z selects weight/output
  gemm_bt_kernel<unsigned short><<<dim3(6, 64, 3), dim3(256), 0, stream>>>(
      xb, wqb, wkb, wvb, Qb, Kb, Vb, DM, DM);

  const int nrope = NTOK * (DM / 8);
  rope_kernel<<<dim3((nrope + 255) / 256), dim3(256), 0, stream>>>(Qb, pos, nrope);
  rope_kernel<<<dim3((nrope + 255) / 256), dim3(256), 0, stream>>>(Kb, pos, nrope);

  attn_kernel<<<dim3(SLEN / 64, 4 * NH), dim3(256), 0, stream>>>(Qb, Kb, Vb, Ab);

  // output projection -> fp32
  gemm_bt_kernel<float><<<dim3(6, 64, 1), dim3(256), 0, stream>>>(
      Ab, wob, wob, wob, out, out, out, DM, DM);
}